// Round 3
// baseline (994.199 us; speedup 1.0000x reference)
//
#include <hip/hip_runtime.h>
#include <hip/hip_bf16.h>
#include <cstdint>
#include <cstddef>

// ---------------------------------------------------------------------------
// ChildSumTreeLSTM, complete binary tree N=131071=2^17-1, dim 256.
// Round 3: - pack_level eliminated (GEMM A reads split along K: Xb | H/Hsum)
//          - global_load_lds width-16 staging, XOR-16B-swizzled LDS (no pad)
//          - iou epilogue emits Hsum (sibling pairs are in-lane in C-layout)
//          - 128x192 (iou) / 128x128 (f) tiles, 4 waves 2x2
// Per level L (count parents; children level already produced H, Hsum, C):
//   f:   F = [x_parent | h_child] @ Wf^T; f=sig(F+bfc); FC[p]=f0*c0+f1*c1
//   iou: [x_p | hsum] @ Wiou^T; c=sig(i)tanh(u)+FC; h=sig(o)tanh(c); + Hsum
// Leaf: iou with K=256 (x only). Workspace 185.6 MB (== round-2 footprint).
// ---------------------------------------------------------------------------

typedef __bf16 bf16;
typedef bf16 bf16x8 __attribute__((ext_vector_type(8)));
typedef float f32x4 __attribute__((ext_vector_type(4)));

#define LEAF_START 65535
#define LEAF_COUNT 65536

__device__ __forceinline__ float sigf(float x) { return 1.0f / (1.0f + __expf(-x)); }
__device__ __forceinline__ float tanh_fast(float x) {
  return 1.0f - 2.0f / (__expf(2.0f * x) + 1.0f);
}

// async global->LDS, 16 B per lane, dest = base + lane*16
#define GLD16(g, l) __builtin_amdgcn_global_load_lds(                         \
    (const __attribute__((address_space(1))) void*)(g),                       \
    (__attribute__((address_space(3))) void*)(l), 16, 0, 0)

// Build concatenated bf16 weights + fused fp32 biases.
__global__ void prep_weights(const float* __restrict__ Wioux, const float* __restrict__ Wiouh,
                             const float* __restrict__ Wfx, const float* __restrict__ Wfh,
                             const float* __restrict__ bioux, const float* __restrict__ biouh,
                             const float* __restrict__ bfx, const float* __restrict__ bfh,
                             bf16* __restrict__ Wiou, bf16* __restrict__ Wf,
                             float* __restrict__ biou, float* __restrict__ bfc)
{
  const int el = blockIdx.x * 256 + threadIdx.x;   // 0 .. 524287
  if (el < 768 * 512) {
    const int r = el >> 9, c = el & 511;
    const float v = (c < 256) ? Wioux[r * 256 + c] : Wiouh[r * 256 + c - 256];
    Wiou[el] = (bf16)v;
  } else {
    const int e2 = el - 768 * 512;                 // 0 .. 131071
    const int r = e2 >> 9, c = e2 & 511;
    const float v = (c < 256) ? Wfx[r * 256 + c] : Wfh[r * 256 + c - 256];
    Wf[e2] = (bf16)v;
  }
  if (el < 768)       biou[el] = bioux[el] + biouh[el];
  else if (el < 1024) bfc[el - 768] = bfx[el - 768] + bfh[el - 768];
}

// Convert ALL of X (131071 x 256 fp32) to bf16.
__global__ void convert_x(const float* __restrict__ X, bf16* __restrict__ Xb)
{
  const int i = blockIdx.x * 256 + threadIdx.x;    // float4 index
  if (i < (131071 * 256) / 4) {
    const float4 v = ((const float4*)X)[i];
    union { ushort4 u; bf16 b[4]; } cv;
    cv.b[0] = (bf16)v.x; cv.b[1] = (bf16)v.y; cv.b[2] = (bf16)v.z; cv.b[3] = (bf16)v.w;
    ((ushort4*)Xb)[i] = cv.u;
  }
}

// IOU GEMM: A[M x K] = [ Xb[xbase+row] (K 0..255) | Hsum_in[row] (K 256..511) ]
// B = Wiou (768 x 512, i/o/u parts stride 256). Tile: 128 rows x 64 channels
// (192 cols). Fused epilogue: gates -> C, H, Hsum_out (+ root out).
__global__ __launch_bounds__(256) void iou_gemm(
    const bf16* __restrict__ Xb, int xbase,
    const bf16* __restrict__ Hsin, const bf16* __restrict__ FCb,
    const float* __restrict__ biou, const bf16* __restrict__ Wiou,
    bf16* __restrict__ Cst, bf16* __restrict__ H, bf16* __restrict__ Hsout,
    float* __restrict__ out, int M, int K, int isRoot)
{
  __shared__ bf16 As[128 * 64];
  __shared__ bf16 Bs[192 * 64];
  const int t = threadIdx.x;
  const int wave = t >> 6, lane = t & 63;
  const int quad = lane >> 4, lc = lane & 15;
  const int waveM = wave >> 1, waveN = wave & 1;
  const int mBase = blockIdx.y * 128;
  const int chBase = blockIdx.x * 64;
  const int lrow = lane >> 3;                      // 0..7
  const int lcol8 = ((lane & 7) ^ lrow) << 3;      // swizzled 8-elem block
  const int Mm1 = M - 1;
  f32x4 acc[4][2][3] = {};

  for (int kt = 0; kt < K; kt += 64) {
#pragma unroll
    for (int ii = 0; ii < 10; ++ii) {
      const int issue = wave * 10 + ii;            // 0..15 A, 16..39 B
      if (issue < 16) {
        const int r = issue * 8 + lrow;
        int g = mBase + r; g = g > Mm1 ? Mm1 : g;
        const bf16* src = (kt < 256)
            ? Xb + (size_t)(xbase + g) * 256 + kt + lcol8
            : Hsin + (size_t)g * 256 + (kt - 256) + lcol8;
        GLD16(src, &As[issue * 512]);
      } else {
        const int i2 = issue - 16;                 // 0..23
        const int rb = i2 * 8 + lrow;              // Bs row 0..191
        const int grow = (rb >> 6) * 256 + chBase + (rb & 63);
        GLD16(Wiou + (size_t)grow * 512 + kt + lcol8, &Bs[i2 * 512]);
      }
    }
    __syncthreads();
#pragma unroll
    for (int kk = 0; kk < 64; kk += 32) {
      bf16x8 a[4];
#pragma unroll
      for (int mf = 0; mf < 4; ++mf) {
        const int rA = waveM * 64 + mf * 16 + lc;
        const int lb = (kk >> 3) + quad;
        a[mf] = *(const bf16x8*)&As[rA * 64 + ((lb ^ (rA & 7)) << 3)];
      }
#pragma unroll
      for (int cg = 0; cg < 2; ++cg)
#pragma unroll
        for (int p = 0; p < 3; ++p) {
          const int rB = p * 64 + waveN * 32 + cg * 16 + lc;
          const int lb = (kk >> 3) + quad;
          bf16x8 b = *(const bf16x8*)&Bs[rB * 64 + ((lb ^ (rB & 7)) << 3)];
#pragma unroll
          for (int mf = 0; mf < 4; ++mf)
            acc[mf][cg][p] = __builtin_amdgcn_mfma_f32_16x16x32_bf16(a[mf], b, acc[mf][cg][p], 0, 0, 0);
        }
    }
    __syncthreads();
  }

#pragma unroll
  for (int cg = 0; cg < 2; ++cg) {
    const int ch = chBase + waveN * 32 + cg * 16 + lc;
    const float bi = biou[ch], bo = biou[256 + ch], bu = biou[512 + ch];
#pragma unroll
    for (int mf = 0; mf < 4; ++mf) {
      const int row = mBase + waveM * 64 + mf * 16 + quad * 4;
      float hv[4] = {0.f, 0.f, 0.f, 0.f};
#pragma unroll
      for (int r = 0; r < 4; ++r) {
        const int rw = row + r;
        if (rw < M) {
          const float iv = acc[mf][cg][0][r] + bi;
          const float ov = acc[mf][cg][1][r] + bo;
          const float uv = acc[mf][cg][2][r] + bu;
          const float fc = FCb ? (float)FCb[(size_t)rw * 256 + ch] : 0.0f;
          const float cv = sigf(iv) * tanh_fast(uv) + fc;
          const float h1 = sigf(ov) * tanh_fast(cv);
          hv[r] = h1;
          Cst[(size_t)rw * 256 + ch] = (bf16)cv;
          H[(size_t)rw * 256 + ch] = (bf16)h1;
          if (isRoot && rw == 0) { out[ch] = cv; out[256 + ch] = h1; }
        }
      }
      if (row + 1 < M) Hsout[(size_t)(row >> 1) * 256 + ch] = (bf16)(hv[0] + hv[1]);
      if (row + 3 < M) Hsout[(size_t)((row >> 1) + 1) * 256 + ch] = (bf16)(hv[2] + hv[3]);
    }
  }
}

// F GEMM over children: A[j] = [ Xb[parent(j)] | H[j] ], B = Wf (256 x 512).
// Tile 128 children x 128 cols. Fused: f=sig(F+bfc); FC[j>>1] = f0*c0+f1*c1.
__global__ __launch_bounds__(256) void f_gemm(
    const bf16* __restrict__ Xb, int xbase,
    const bf16* __restrict__ H, const bf16* __restrict__ Cc,
    const float* __restrict__ bfc, const bf16* __restrict__ Wf,
    bf16* __restrict__ FCb, int M2)
{
  __shared__ bf16 As[128 * 64];
  __shared__ bf16 Bs[128 * 64];
  const int t = threadIdx.x;
  const int wave = t >> 6, lane = t & 63;
  const int quad = lane >> 4, lc = lane & 15;
  const int waveM = wave >> 1, waveN = wave & 1;
  const int mBase = blockIdx.y * 128;
  const int nBase = blockIdx.x * 128;
  const int lrow = lane >> 3;
  const int lcol8 = ((lane & 7) ^ lrow) << 3;
  const int Mm1 = M2 - 1;
  f32x4 acc[4][4] = {};

  for (int kt = 0; kt < 512; kt += 64) {
#pragma unroll
    for (int ii = 0; ii < 8; ++ii) {
      const int issue = wave * 8 + ii;             // 0..15 A, 16..31 B
      if (issue < 16) {
        const int r = issue * 8 + lrow;
        int j = mBase + r; j = j > Mm1 ? Mm1 : j;
        const bf16* src = (kt < 256)
            ? Xb + (size_t)(xbase + (j >> 1)) * 256 + kt + lcol8
            : H + (size_t)j * 256 + (kt - 256) + lcol8;
        GLD16(src, &As[issue * 512]);
      } else {
        const int rb = (issue - 16) * 8 + lrow;    // 0..127
        GLD16(Wf + (size_t)(nBase + rb) * 512 + kt + lcol8, &Bs[(issue - 16) * 512]);
      }
    }
    __syncthreads();
#pragma unroll
    for (int kk = 0; kk < 64; kk += 32) {
      bf16x8 a[4];
#pragma unroll
      for (int mf = 0; mf < 4; ++mf) {
        const int rA = waveM * 64 + mf * 16 + lc;
        const int lb = (kk >> 3) + quad;
        a[mf] = *(const bf16x8*)&As[rA * 64 + ((lb ^ (rA & 7)) << 3)];
      }
#pragma unroll
      for (int nf = 0; nf < 4; ++nf) {
        const int rB = waveN * 64 + nf * 16 + lc;
        const int lb = (kk >> 3) + quad;
        bf16x8 b = *(const bf16x8*)&Bs[rB * 64 + ((lb ^ (rB & 7)) << 3)];
#pragma unroll
        for (int mf = 0; mf < 4; ++mf)
          acc[mf][nf] = __builtin_amdgcn_mfma_f32_16x16x32_bf16(a[mf], b, acc[mf][nf], 0, 0, 0);
      }
    }
    __syncthreads();
  }

#pragma unroll
  for (int nf = 0; nf < 4; ++nf) {
    const int col = nBase + waveN * 64 + nf * 16 + lc;
    const float bv = bfc[col];
#pragma unroll
    for (int mf = 0; mf < 4; ++mf) {
      const int j0 = mBase + waveM * 64 + mf * 16 + quad * 4;
#pragma unroll
      for (int p = 0; p < 4; p += 2) {
        const int j = j0 + p;
        if (j < M2) {
          const float f0 = sigf(acc[mf][nf][p] + bv);
          const float f1 = sigf(acc[mf][nf][p + 1] + bv);
          const float c0 = (float)Cc[(size_t)j * 256 + col];
          const float c1 = (float)Cc[(size_t)(j + 1) * 256 + col];
          FCb[(size_t)(j >> 1) * 256 + col] = (bf16)(f0 * c0 + f1 * c1);
        }
      }
    }
  }
}

extern "C" void kernel_launch(void* const* d_in, const int* in_sizes, int n_in,
                              void* d_out, int out_size, void* d_ws, size_t ws_size,
                              hipStream_t stream)
{
  const float* X      = (const float*)d_in[0];
  const float* Wioux  = (const float*)d_in[1];
  const float* bioux  = (const float*)d_in[2];
  const float* Wiouh  = (const float*)d_in[3];
  const float* biouh  = (const float*)d_in[4];
  const float* Wfx    = (const float*)d_in[5];
  const float* bfx    = (const float*)d_in[6];
  const float* Wfh    = (const float*)d_in[7];
  const float* bfh    = (const float*)d_in[8];
  float* out = (float*)d_out;
  (void)in_sizes; (void)n_in; (void)out_size; (void)ws_size;

  // workspace: 185.6 MB (== round-2 proven footprint)
  char* ws = (char*)d_ws;
  size_t off = 0;
  auto alloc = [&](size_t bytes) -> char* {
    char* p = ws + off;
    off += (bytes + 255) & ~(size_t)255;
    return p;
  };
  bf16*  Wiou = (bf16*)alloc((size_t)768 * 512 * 2);
  bf16*  Wf   = (bf16*)alloc((size_t)256 * 512 * 2);
  float* biou = (float*)alloc(768 * 4);
  float* bfc  = (float*)alloc(256 * 4);
  bf16*  Xb   = (bf16*)alloc((size_t)131071 * 256 * 2);  // 67.1 MB
  bf16*  H    = (bf16*)alloc((size_t)65536 * 256 * 2);   // 33.6 MB (level-local)
  bf16*  HsA  = (bf16*)alloc((size_t)32768 * 256 * 2);   // 16.8 MB
  bf16*  HsB  = (bf16*)alloc((size_t)32768 * 256 * 2);   // 16.8 MB
  bf16*  FCb  = (bf16*)alloc((size_t)32768 * 256 * 2);   // 16.8 MB
  bf16*  C    = (bf16*)alloc((size_t)65536 * 256 * 2);   // 33.6 MB (level-local)

  prep_weights<<<2048, 256, 0, stream>>>(Wioux, Wiouh, Wfx, Wfh,
                                         bioux, biouh, bfx, bfh,
                                         Wiou, Wf, biou, bfc);
  convert_x<<<32768, 256, 0, stream>>>(X, Xb);

  // Leaf level: K=256 (x only), writes C/H rows [0,65536) and HsA [0,32768)
  iou_gemm<<<dim3(4, 512), 256, 0, stream>>>(
      Xb, LEAF_START, HsA /*unused*/, nullptr, biou, Wiou,
      C, H, HsA, out, LEAF_COUNT, 256, 0);

  // Internal levels, bottom-up. Stream order guarantees:
  //   f L reads H/C of children (written by level L+1) before iou L overwrites.
  for (int lvl = 15; lvl >= 0; --lvl) {
    const int count = 1 << lvl;
    const int s = count - 1;
    const int M2 = 2 * count;
    const bf16* Hsin = (lvl & 1) ? HsA : HsB;   // leaf wrote HsA; lvl15 reads it
    bf16* Hsout      = (lvl & 1) ? HsB : HsA;
    f_gemm<<<dim3(2, (M2 + 127) / 128), 256, 0, stream>>>(
        Xb, s, H, C, bfc, Wf, FCb, M2);
    iou_gemm<<<dim3(4, (count + 127) / 128), 256, 0, stream>>>(
        Xb, s, Hsin, FCb, biou, Wiou, C, H, Hsout, out, count, 512, lvl == 0);
  }
}

// Round 4
// 863.963 us; speedup vs baseline: 1.1507x; 1.1507x over previous
//
#include <hip/hip_runtime.h>
#include <hip/hip_bf16.h>
#include <cstdint>
#include <cstddef>

// ---------------------------------------------------------------------------
// ChildSumTreeLSTM, complete binary tree N=131071=2^17-1, dim 256.
// Round 4: round-3 structure (GLD16 staging, XOR-swizzled LDS, no pack kernel)
// with m97-profile register/LDS budgets restored (round-3 post-mortem: 96-AGPR
// acc tile -> 2 blocks/CU -> latency-bound).
//   iou: 128 rows x 32 ch (96 cols = 3 parts x 32), acc 48 AGPR, LDS 28 KB
//   f:   128 rows x 128 cols, acc 64 AGPR, LDS 32 KB
// K-loop split into two static phases (Xb | Hs/H) - no per-kt select VALU.
// ---------------------------------------------------------------------------

typedef __bf16 bf16;
typedef bf16 bf16x8 __attribute__((ext_vector_type(8)));
typedef float f32x4 __attribute__((ext_vector_type(4)));

#define LEAF_START 65535
#define LEAF_COUNT 65536

__device__ __forceinline__ float sigf(float x) { return 1.0f / (1.0f + __expf(-x)); }
__device__ __forceinline__ float tanh_fast(float x) {
  return 1.0f - 2.0f / (__expf(2.0f * x) + 1.0f);
}

// async global->LDS, 16 B per lane, dest = base + lane*16
#define GLD16(g, l) __builtin_amdgcn_global_load_lds(                         \
    (const __attribute__((address_space(1))) void*)(g),                       \
    (__attribute__((address_space(3))) void*)(l), 16, 0, 0)

__global__ void prep_weights(const float* __restrict__ Wioux, const float* __restrict__ Wiouh,
                             const float* __restrict__ Wfx, const float* __restrict__ Wfh,
                             const float* __restrict__ bioux, const float* __restrict__ biouh,
                             const float* __restrict__ bfx, const float* __restrict__ bfh,
                             bf16* __restrict__ Wiou, bf16* __restrict__ Wf,
                             float* __restrict__ biou, float* __restrict__ bfc)
{
  const int el = blockIdx.x * 256 + threadIdx.x;   // 0 .. 524287
  if (el < 768 * 512) {
    const int r = el >> 9, c = el & 511;
    const float v = (c < 256) ? Wioux[r * 256 + c] : Wiouh[r * 256 + c - 256];
    Wiou[el] = (bf16)v;
  } else {
    const int e2 = el - 768 * 512;
    const int r = e2 >> 9, c = e2 & 511;
    const float v = (c < 256) ? Wfx[r * 256 + c] : Wfh[r * 256 + c - 256];
    Wf[e2] = (bf16)v;
  }
  if (el < 768)       biou[el] = bioux[el] + biouh[el];
  else if (el < 1024) bfc[el - 768] = bfx[el - 768] + bfh[el - 768];
}

__global__ void convert_x(const float* __restrict__ X, bf16* __restrict__ Xb)
{
  const int i = blockIdx.x * 256 + threadIdx.x;    // float4 index
  if (i < (131071 * 256) / 4) {
    const float4 v = ((const float4*)X)[i];
    union { ushort4 u; bf16 b[4]; } cv;
    cv.b[0] = (bf16)v.x; cv.b[1] = (bf16)v.y; cv.b[2] = (bf16)v.z; cv.b[3] = (bf16)v.w;
    ((ushort4*)Xb)[i] = cv.u;
  }
}

// IOU GEMM: A[M x K] = [ Xb[xbase+row] | Hsin[row] ], B = Wiou (768 x 512).
// Tile: 128 rows x 32 channels (96 cols: part*32+ch). Each wave: 64 rows
// (waveM) x 16 channels (waveN) x 3 parts -> lane-local i,o,u.
// Epilogue: c = sig(i)tanh(u) + FC; h = sig(o)tanh(c); emit C, H, Hsum.
__global__ __launch_bounds__(256) void iou_gemm(
    const bf16* __restrict__ Xb, int xbase,
    const bf16* __restrict__ Hsin, const bf16* __restrict__ FCb,
    const float* __restrict__ biou, const bf16* __restrict__ Wiou,
    bf16* __restrict__ Cst, bf16* __restrict__ H, bf16* __restrict__ Hsout,
    float* __restrict__ out, int M, int K, int isRoot)
{
  __shared__ bf16 As[128 * 64];   // 16 KB
  __shared__ bf16 Bs[96 * 64];    // 12 KB
  const int t = threadIdx.x;
  const int wave = t >> 6, lane = t & 63;
  const int quad = lane >> 4, lc = lane & 15;
  const int waveM = wave >> 1, waveN = wave & 1;
  const int mBase = blockIdx.y * 128;
  const int chBase = blockIdx.x * 32;
  const int lrow = lane >> 3;                      // 0..7
  const int lcol8 = ((lane & 7) ^ lrow) << 3;      // swizzled 8-elem block
  const int Mm1 = M - 1;
  f32x4 acc[4][3] = {};

  auto ktile = [&](const bf16* __restrict__ abase, int ka, int kb) {
    // A: 16 issues (8 rows each); this wave does 4
#pragma unroll
    for (int ii = 0; ii < 4; ++ii) {
      const int idx = wave * 4 + ii;
      const int r = idx * 8 + lrow;
      int g = mBase + r; g = g > Mm1 ? Mm1 : g;
      GLD16(abase + (size_t)g * 256 + ka + lcol8, &As[idx * 512]);
    }
    // B: 12 issues; this wave does 3
#pragma unroll
    for (int ii = 0; ii < 3; ++ii) {
      const int idx = wave * 3 + ii;
      const int rb = idx * 8 + lrow;               // 0..95
      const int grow = (rb >> 5) * 256 + chBase + (rb & 31);
      GLD16(Wiou + (size_t)grow * 512 + kb + lcol8, &Bs[idx * 512]);
    }
    __syncthreads();
#pragma unroll
    for (int kk = 0; kk < 64; kk += 32) {
      const int lb = (kk >> 3) + quad;
      bf16x8 a[4];
#pragma unroll
      for (int mf = 0; mf < 4; ++mf) {
        const int rA = waveM * 64 + mf * 16 + lc;
        a[mf] = *(const bf16x8*)&As[rA * 64 + ((lb ^ (rA & 7)) << 3)];
      }
#pragma unroll
      for (int p = 0; p < 3; ++p) {
        const int rB = p * 32 + waveN * 16 + lc;
        bf16x8 b = *(const bf16x8*)&Bs[rB * 64 + ((lb ^ (rB & 7)) << 3)];
#pragma unroll
        for (int mf = 0; mf < 4; ++mf)
          acc[mf][p] = __builtin_amdgcn_mfma_f32_16x16x32_bf16(a[mf], b, acc[mf][p], 0, 0, 0);
      }
    }
    __syncthreads();
  };

#pragma unroll
  for (int kt = 0; kt < 256; kt += 64) ktile(Xb + (size_t)xbase * 256, kt, kt);
  if (K == 512) {
#pragma unroll
    for (int kt = 0; kt < 256; kt += 64) ktile(Hsin, kt, kt + 256);
  }

  const int ch = chBase + waveN * 16 + lc;
  const float bi = biou[ch], bo = biou[256 + ch], bu = biou[512 + ch];
#pragma unroll
  for (int mf = 0; mf < 4; ++mf) {
    const int row0 = mBase + waveM * 64 + mf * 16 + quad * 4;
    float hv[4] = {0.f, 0.f, 0.f, 0.f};
#pragma unroll
    for (int r = 0; r < 4; ++r) {
      const int rw = row0 + r;
      if (rw < M) {
        const float iv = acc[mf][0][r] + bi;
        const float ov = acc[mf][1][r] + bo;
        const float uv = acc[mf][2][r] + bu;
        const float fc = FCb ? (float)FCb[(size_t)rw * 256 + ch] : 0.0f;
        const float cv = sigf(iv) * tanh_fast(uv) + fc;
        const float h1 = sigf(ov) * tanh_fast(cv);
        hv[r] = h1;
        Cst[(size_t)rw * 256 + ch] = (bf16)cv;
        H[(size_t)rw * 256 + ch] = (bf16)h1;
        if (isRoot && rw == 0) { out[ch] = cv; out[256 + ch] = h1; }
      }
    }
    if (row0 + 1 < M) Hsout[(size_t)(row0 >> 1) * 256 + ch] = (bf16)(hv[0] + hv[1]);
    if (row0 + 3 < M) Hsout[(size_t)((row0 >> 1) + 1) * 256 + ch] = (bf16)(hv[2] + hv[3]);
  }
}

// F GEMM over children: A[j] = [ Xb[parent(j)] | H[j] ], B = Wf (256 x 512).
// m97 profile: 128 x 128 tile, waves 2x2, acc 64. Fused: FC = f0*c0 + f1*c1.
__global__ __launch_bounds__(256) void f_gemm(
    const bf16* __restrict__ Xb, int xbase,
    const bf16* __restrict__ H, const bf16* __restrict__ Cc,
    const float* __restrict__ bfc, const bf16* __restrict__ Wf,
    bf16* __restrict__ FCb, int M2)
{
  __shared__ bf16 As[128 * 64];
  __shared__ bf16 Bs[128 * 64];
  const int t = threadIdx.x;
  const int wave = t >> 6, lane = t & 63;
  const int quad = lane >> 4, lc = lane & 15;
  const int waveM = wave >> 1, waveN = wave & 1;
  const int mBase = blockIdx.y * 128;
  const int nBase = blockIdx.x * 128;
  const int lrow = lane >> 3;
  const int lcol8 = ((lane & 7) ^ lrow) << 3;
  const int Mm1 = M2 - 1;
  f32x4 acc[4][4] = {};

  auto ktile = [&](bool xphase, int ka, int kb) {
#pragma unroll
    for (int ii = 0; ii < 4; ++ii) {
      const int idx = wave * 4 + ii;
      const int r = idx * 8 + lrow;
      int j = mBase + r; j = j > Mm1 ? Mm1 : j;
      const bf16* src = xphase ? Xb + (size_t)(xbase + (j >> 1)) * 256 + ka + lcol8
                               : H + (size_t)j * 256 + ka + lcol8;
      GLD16(src, &As[idx * 512]);
    }
#pragma unroll
    for (int ii = 0; ii < 4; ++ii) {
      const int idx = wave * 4 + ii;
      const int rb = idx * 8 + lrow;
      GLD16(Wf + (size_t)(nBase + rb) * 512 + kb + lcol8, &Bs[idx * 512]);
    }
    __syncthreads();
#pragma unroll
    for (int kk = 0; kk < 64; kk += 32) {
      const int lb = (kk >> 3) + quad;
      bf16x8 a[4];
#pragma unroll
      for (int mf = 0; mf < 4; ++mf) {
        const int rA = waveM * 64 + mf * 16 + lc;
        a[mf] = *(const bf16x8*)&As[rA * 64 + ((lb ^ (rA & 7)) << 3)];
      }
#pragma unroll
      for (int nf = 0; nf < 4; ++nf) {
        const int rB = waveN * 64 + nf * 16 + lc;
        bf16x8 b = *(const bf16x8*)&Bs[rB * 64 + ((lb ^ (rB & 7)) << 3)];
#pragma unroll
        for (int mf = 0; mf < 4; ++mf)
          acc[mf][nf] = __builtin_amdgcn_mfma_f32_16x16x32_bf16(a[mf], b, acc[mf][nf], 0, 0, 0);
      }
    }
    __syncthreads();
  };

#pragma unroll
  for (int kt = 0; kt < 256; kt += 64) ktile(true, kt, kt);
#pragma unroll
  for (int kt = 0; kt < 256; kt += 64) ktile(false, kt, kt + 256);

#pragma unroll
  for (int nf = 0; nf < 4; ++nf) {
    const int col = nBase + waveN * 64 + nf * 16 + lc;
    const float bv = bfc[col];
#pragma unroll
    for (int mf = 0; mf < 4; ++mf) {
      const int j0 = mBase + waveM * 64 + mf * 16 + quad * 4;
#pragma unroll
      for (int p = 0; p < 4; p += 2) {
        const int j = j0 + p;
        if (j < M2) {
          const float f0 = sigf(acc[mf][nf][p] + bv);
          const float f1 = sigf(acc[mf][nf][p + 1] + bv);
          const float c0 = (float)Cc[(size_t)j * 256 + col];
          const float c1 = (float)Cc[(size_t)(j + 1) * 256 + col];
          FCb[(size_t)(j >> 1) * 256 + col] = (bf16)(f0 * c0 + f1 * c1);
        }
      }
    }
  }
}

extern "C" void kernel_launch(void* const* d_in, const int* in_sizes, int n_in,
                              void* d_out, int out_size, void* d_ws, size_t ws_size,
                              hipStream_t stream)
{
  const float* X      = (const float*)d_in[0];
  const float* Wioux  = (const float*)d_in[1];
  const float* bioux  = (const float*)d_in[2];
  const float* Wiouh  = (const float*)d_in[3];
  const float* biouh  = (const float*)d_in[4];
  const float* Wfx    = (const float*)d_in[5];
  const float* bfx    = (const float*)d_in[6];
  const float* Wfh    = (const float*)d_in[7];
  const float* bfh    = (const float*)d_in[8];
  float* out = (float*)d_out;
  (void)in_sizes; (void)n_in; (void)out_size; (void)ws_size;

  // workspace: 185.6 MB (proven footprint)
  char* ws = (char*)d_ws;
  size_t off = 0;
  auto alloc = [&](size_t bytes) -> char* {
    char* p = ws + off;
    off += (bytes + 255) & ~(size_t)255;
    return p;
  };
  bf16*  Wiou = (bf16*)alloc((size_t)768 * 512 * 2);
  bf16*  Wf   = (bf16*)alloc((size_t)256 * 512 * 2);
  float* biou = (float*)alloc(768 * 4);
  float* bfc  = (float*)alloc(256 * 4);
  bf16*  Xb   = (bf16*)alloc((size_t)131071 * 256 * 2);  // 67.1 MB
  bf16*  H    = (bf16*)alloc((size_t)65536 * 256 * 2);   // 33.6 MB (level-local)
  bf16*  HsA  = (bf16*)alloc((size_t)32768 * 256 * 2);   // 16.8 MB
  bf16*  HsB  = (bf16*)alloc((size_t)32768 * 256 * 2);   // 16.8 MB
  bf16*  FCb  = (bf16*)alloc((size_t)32768 * 256 * 2);   // 16.8 MB
  bf16*  C    = (bf16*)alloc((size_t)65536 * 256 * 2);   // 33.6 MB (level-local)

  prep_weights<<<2048, 256, 0, stream>>>(Wioux, Wiouh, Wfx, Wfh,
                                         bioux, biouh, bfx, bfh,
                                         Wiou, Wf, biou, bfc);
  convert_x<<<32768, 256, 0, stream>>>(X, Xb);

  // Leaf level: K=256 (x only); writes C/H rows [0,65536), HsA [0,32768)
  iou_gemm<<<dim3(8, 512), 256, 0, stream>>>(
      Xb, LEAF_START, HsA /*unused*/, nullptr, biou, Wiou,
      C, H, HsA, out, LEAF_COUNT, 256, 0);

  // Internal levels, bottom-up.
  for (int lvl = 15; lvl >= 0; --lvl) {
    const int count = 1 << lvl;
    const int s = count - 1;
    const int M2 = 2 * count;
    const bf16* Hsin = (lvl & 1) ? HsA : HsB;
    bf16* Hsout      = (lvl & 1) ? HsB : HsA;
    f_gemm<<<dim3(2, (M2 + 127) / 128), 256, 0, stream>>>(
        Xb, s, H, C, bfc, Wf, FCb, M2);
    iou_gemm<<<dim3(8, (count + 127) / 128), 256, 0, stream>>>(
        Xb, s, Hsin, FCb, biou, Wiou, C, H, Hsout, out, count, 512, lvl == 0);
  }
}